// Round 5
// baseline (1671.967 us; speedup 1.0000x reference)
//
#include <hip/hip_runtime.h>

#define NN 100000
#define NSTEP 5
#define NBLK 256
#define LSTR 264   // ushorts; 528B rows, 16B aligned for ds_read_b128

typedef unsigned short ushort_t;
typedef __attribute__((ext_vector_type(8))) short short8;
typedef __attribute__((ext_vector_type(4))) float floatx4;

__device__ __forceinline__ ushort_t f2bf(float f){
  union { float f; unsigned u; } v; v.f = f;
  unsigned r = v.u + 0x7fffu + ((v.u >> 16) & 1u);
  return (ushort_t)(r >> 16);
}
__device__ __forceinline__ float bf2f(ushort_t s){
  union { unsigned u; float f; } v; v.u = ((unsigned)s) << 16;
  return v.f;
}
__device__ __forceinline__ float sigf(float x){ return 1.0f/(1.0f+__expf(-x)); }

// ---------------- device-scope global barrier (all NBLK blocks co-resident) ----------------
__device__ __forceinline__ void gbar(int* cnt, int* gen){
  __syncthreads();
  if (threadIdx.x == 0){
    __threadfence();                       // release: drain our writes to coherent point
    int g = atomicAdd(gen, 0);
    if (atomicAdd(cnt, 1) == NBLK - 1){
      atomicExch(cnt, 0);
      atomicAdd(gen, 1);
    } else {
      int guard = 0;
      while (atomicAdd(gen, 0) == g){
        __builtin_amdgcn_s_sleep(1);
        if (++guard > 200000000) break;    // safety: no hang on bug
      }
    }
    __threadfence();                       // acquire: invalidate stale cached lines
  }
  __syncthreads();
}

// ================= fused FNN: hfeat = (elu(x@W1+b1))@W2+b2, bf16 out =================
// 1563 blocks x 256 thr (4 waves), 64 rows x 256 cols, 33.8 KB LDS -> 4 blocks/CU.
__global__ __launch_bounds__(256, 4) void fnn_fused(const float* __restrict__ x,
    const ushort_t* __restrict__ W1T, const float* __restrict__ b1,
    const ushort_t* __restrict__ W2T, const float* __restrict__ b2,
    ushort_t* __restrict__ hfeat, int M)
{
  __shared__ ushort_t buf[64 * LSTR];
  int tid = threadIdx.x;
  int w = tid >> 6, lane = tid & 63, qd = lane >> 4, r16 = lane & 15;
  int row0 = blockIdx.x * 64;
  int col0 = w * 64;

  // ---- stage x tile (64x256 fp32 -> bf16 LDS): 4096 float4 over 256 thr ----
  #pragma unroll
  for (int it = 0; it < 16; it++){
    int idx = it * 256 + tid;
    int r = idx >> 6, c4 = idx & 63;
    int rg = row0 + r; if (rg >= M) rg = M - 1;
    float4 v = *(const float4*)(x + (size_t)rg * 256 + c4 * 4);
    ushort4 pk = make_ushort4(f2bf(v.x), f2bf(v.y), f2bf(v.z), f2bf(v.w));
    *(ushort4*)&buf[r * LSTR + c4 * 4] = pk;
  }
  __syncthreads();

  floatx4 acc[4][4];

  // ---- GEMM1 ----
  #pragma unroll
  for (int i=0;i<4;i++)
    #pragma unroll
    for (int j=0;j<4;j++) acc[i][j] = (floatx4){0.f,0.f,0.f,0.f};

  for (int kk = 0; kk < 256; kk += 32){
    short8 af[4], bfr[4];
    #pragma unroll
    for (int i=0;i<4;i++)
      af[i] = *(const short8*)&buf[(i*16 + r16) * LSTR + kk + qd*8];
    #pragma unroll
    for (int j=0;j<4;j++)
      bfr[j] = *(const short8*)(W1T + (size_t)(col0 + j*16 + r16) * 256 + kk + qd*8);
    #pragma unroll
    for (int i=0;i<4;i++)
      #pragma unroll
      for (int j=0;j<4;j++)
        acc[i][j] = __builtin_amdgcn_mfma_f32_16x16x32_bf16(af[i], bfr[j], acc[i][j], 0, 0, 0);
  }
  __syncthreads();

  // ---- ELU (fast exp) -> t tile in same LDS ----
  #pragma unroll
  for (int i=0;i<4;i++){
    #pragma unroll
    for (int j=0;j<4;j++){
      int col = col0 + j*16 + r16;
      float bb = b1[col];
      #pragma unroll
      for (int rr=0;rr<4;rr++){
        int row = i*16 + qd*4 + rr;
        float v = acc[i][j][rr] + bb;
        v = v > 0.f ? v : (__expf(v) - 1.0f);
        buf[row * LSTR + col] = f2bf(v);
      }
    }
  }
  __syncthreads();

  // ---- GEMM2 ----
  #pragma unroll
  for (int i=0;i<4;i++)
    #pragma unroll
    for (int j=0;j<4;j++) acc[i][j] = (floatx4){0.f,0.f,0.f,0.f};

  for (int kk = 0; kk < 256; kk += 32){
    short8 af[4], bfr[4];
    #pragma unroll
    for (int i=0;i<4;i++)
      af[i] = *(const short8*)&buf[(i*16 + r16) * LSTR + kk + qd*8];
    #pragma unroll
    for (int j=0;j<4;j++)
      bfr[j] = *(const short8*)(W2T + (size_t)(col0 + j*16 + r16) * 256 + kk + qd*8);
    #pragma unroll
    for (int i=0;i<4;i++)
      #pragma unroll
      for (int j=0;j<4;j++)
        acc[i][j] = __builtin_amdgcn_mfma_f32_16x16x32_bf16(af[i], bfr[j], acc[i][j], 0, 0, 0);
  }

  #pragma unroll
  for (int i=0;i<4;i++){
    #pragma unroll
    for (int j=0;j<4;j++){
      int col = col0 + j*16 + r16;
      float bb = b2[col];
      #pragma unroll
      for (int rr=0;rr<4;rr++){
        int row = row0 + i*16 + qd*4 + rr;
        if (row < M) hfeat[(size_t)row * 256 + col] = f2bf(acc[i][j][rr] + bb);
      }
    }
  }
}

// ---------------- LSTM tile (blocks 0..127): 8-wave K-split GEMM + fused cell ----------------
__device__ __forceinline__ void lstm_block(int bid, int tid,
    const ushort_t* __restrict__ A, int lda,
    const ushort_t* __restrict__ Wc, const float* __restrict__ bcp, int K,
    float* __restrict__ c, ushort_t* dstA, int sA, ushort_t* dstB, int sB,
    float* qdst, float* sb)
{
  int w = tid >> 6, lane = tid & 63, qd = lane >> 4, r16 = lane & 15;
  int m0 = (bid & 7) * 16, n0 = (bid >> 3) * 16;
  int kq = K >> 3;                    // 96 (K=768) or 64 (K=512)
  int kbeg = w * kq;
  floatx4 acc[4];
  #pragma unroll
  for (int g=0; g<4; g++) acc[g] = (floatx4){0.f,0.f,0.f,0.f};

  const ushort_t* Ar = A + (size_t)(m0 + r16) * lda + qd * 8;
  for (int kk = kbeg; kk < kbeg + kq; kk += 32){
    short8 av = *(const short8*)(Ar + kk);
    #pragma unroll
    for (int g = 0; g < 4; g++){
      short8 bv = *(const short8*)(Wc + (size_t)(g*256 + n0 + r16) * K + kk + qd*8);
      acc[g] = __builtin_amdgcn_mfma_f32_16x16x32_bf16(av, bv, acc[g], 0, 0, 0);
    }
  }
  if (w){
    #pragma unroll
    for (int g=0; g<4; g++) *(floatx4*)&sb[((w-1)*4 + g)*256 + lane*4] = acc[g];
  }
  __syncthreads();
  if (w == 0){
    #pragma unroll
    for (int g=0; g<4; g++)
      #pragma unroll
      for (int t=0; t<7; t++){
        floatx4 p = *(floatx4*)&sb[(t*4 + g)*256 + lane*4];
        acc[g] = acc[g] + p;
      }
    int h = n0 + r16;
    float bci = bcp[h], bcf = bcp[256+h], bcg = bcp[512+h], bco = bcp[768+h];
    #pragma unroll
    for (int rr=0; rr<4; rr++){
      int row = m0 + qd*4 + rr;
      float gi = acc[0][rr] + bci;
      float gf = acc[1][rr] + bcf;
      float gg = acc[2][rr] + bcg;
      float go = acc[3][rr] + bco;
      float cp = c[row*256 + h];
      float cn = sigf(gf)*cp + sigf(gi)*tanhf(gg);
      float hn = sigf(go)*tanhf(cn);
      c[row*256 + h] = cn;
      ushort_t hb = f2bf(hn);
      dstA[row*sA + h] = hb;
      dstB[row*sB + h] = hb;
      if (qdst) qdst[row*512 + h] = hn;
    }
  }
}

// ================= mega: whole 5-step loop + final GEMM, one dispatch =================
__global__ __launch_bounds__(512) void mega(
    const ushort_t* __restrict__ hfeat, const int* __restrict__ bidx,
    const int* __restrict__ seg,
    const ushort_t* __restrict__ Wc0, const ushort_t* __restrict__ Wc1,
    const ushort_t* __restrict__ Wc2, const float* __restrict__ bc,
    float* __restrict__ c_all, ushort_t* __restrict__ xc,
    float* __restrict__ q_star, float* __restrict__ e_ws, float* __restrict__ r_ws,
    const float* __restrict__ outW, const float* __restrict__ outb,
    float* __restrict__ out, int* bar)
{
  __shared__ float sb[7*4*256];       // 28 KB: LSTM reduce scratch
  __shared__ float red[8];
  __shared__ float bcast0;

  int tid = threadIdx.x, bid = blockIdx.x;
  int w = tid >> 6, lane = tid & 63;
  int* cnt = bar; int* gen = bar + 1;

  ushort_t* xc0 = xc;
  ushort_t* xc1 = xc + 98304;
  ushort_t* xc2 = xc + 163840;
  float* c0 = c_all, *c1 = c_all + 32768, *c2 = c_all + 65536;
  const float* bc0 = bc, *bc1 = bc + 1024, *bc2 = bc + 2048;

  for (int s = 0; s < NSTEP; s++){
    // ---- L0 / L1 / L2 (blocks 0..127) ----
    if (bid < 128) lstm_block(bid, tid, xc0, 768, Wc0, bc0, 768, c0, xc0 + 512, 768, xc1, 512, nullptr, sb);
    gbar(cnt, gen);
    if (bid < 128) lstm_block(bid, tid, xc1, 512, Wc1, bc1, 512, c1, xc1 + 256, 512, xc2, 512, nullptr, sb);
    gbar(cnt, gen);
    if (bid < 128) lstm_block(bid, tid, xc2, 512, Wc2, bc2, 512, c2, xc2 + 256, 512, xc0, 768, q_star, sb);
    gbar(cnt, gen);

    // ---- E: e[n] = dot(hfeat[n], q[bidx[n]]), 2048 waves, 2 rows/iter ----
    {
      int gw = bid*8 + w;
      for (int n = gw*2; n < NN; n += 2*2048){
        int n2 = n + 1;
        int b1i = bidx[n], b2i = bidx[n2];
        ushort4 h1 = *(const ushort4*)(hfeat + (size_t)n *256 + lane*4);
        ushort4 h2 = *(const ushort4*)(hfeat + (size_t)n2*256 + lane*4);
        float4 q1 = *(const float4*)(q_star + (size_t)b1i*512 + lane*4);
        float4 q2 = *(const float4*)(q_star + (size_t)b2i*512 + lane*4);
        float d1 = bf2f(h1.x)*q1.x + bf2f(h1.y)*q1.y + bf2f(h1.z)*q1.z + bf2f(h1.w)*q1.w;
        float d2 = bf2f(h2.x)*q2.x + bf2f(h2.y)*q2.y + bf2f(h2.z)*q2.z + bf2f(h2.w)*q2.w;
        #pragma unroll
        for (int off = 32; off; off >>= 1){
          d1 += __shfl_xor(d1, off);
          d2 += __shfl_xor(d2, off);
        }
        if (lane == 0){ e_ws[n] = d1; e_ws[n2] = d2; }
      }
    }
    gbar(cnt, gen);

    // ---- S: segment softmax stats + in-place normalize (blocks 0..127); zero r (128..255) ----
    if (bid < 128){
      int s0 = seg[bid], en = seg[bid+1];
      float m = -INFINITY;
      for (int i = s0 + tid; i < en; i += 512) m = fmaxf(m, e_ws[i]);
      #pragma unroll
      for (int off = 32; off; off >>= 1) m = fmaxf(m, __shfl_xor(m, off));
      if (lane == 0) red[w] = m;
      __syncthreads();
      if (tid == 0){
        float mm = -INFINITY;
        #pragma unroll
        for (int i=0;i<8;i++) mm = fmaxf(mm, red[i]);
        bcast0 = (en > s0) ? mm : 0.f;
      }
      __syncthreads();
      m = bcast0;
      __syncthreads();
      float ls = 0.f;
      for (int i = s0 + tid; i < en; i += 512) ls += __expf(e_ws[i] - m);
      #pragma unroll
      for (int off = 32; off; off >>= 1) ls += __shfl_xor(ls, off);
      if (lane == 0) red[w] = ls;
      __syncthreads();
      if (tid == 0){
        float sum = 1e-16f;
        #pragma unroll
        for (int i=0;i<8;i++) sum += red[i];
        bcast0 = 1.0f / sum;
      }
      __syncthreads();
      float inv = bcast0;
      for (int i = s0 + tid; i < en; i += 512) e_ws[i] = __expf(e_ws[i] - m) * inv;
    } else {
      if (tid < 256) r_ws[(bid-128)*256 + tid] = 0.f;
    }
    gbar(cnt, gen);

    // ---- R: r[b] += a[n]*hfeat[n], node-parallel chunks, atomic flush ----
    {
      const int chunk = (NN + NBLK - 1) / NBLK;      // 391
      int n0 = bid * chunk;
      int nend = n0 + chunk; if (nend > NN) nend = NN;
      int len = nend - n0;
      if (len > 0){
        int mid = n0 + ((len + 1) >> 1);
        int half = tid >> 8, f = tid & 255;
        int lo = half ? mid : n0, hi = half ? nend : mid;
        if (lo < hi){
          int bcur = bidx[lo];
          float acc = 0.f;
          for (int n = lo; n < hi; n++){
            int b = bidx[n];
            if (b != bcur){
              atomicAdd(&r_ws[bcur*256 + f], acc);
              acc = 0.f; bcur = b;
            }
            acc += e_ws[n] * bf2f(hfeat[(size_t)n*256 + f]);
          }
          atomicAdd(&r_ws[bcur*256 + f], acc);
        }
      }
    }
    gbar(cnt, gen);

    // ---- F: finalize r -> q_star[:,256:], xc0[:,256:512] (blocks 0..127) ----
    if (bid < 128 && tid < 256){
      float v = r_ws[bid*256 + tid];
      q_star[bid*512 + 256 + tid] = v;
      xc0[bid*768 + 256 + tid] = f2bf(v);
    }
    gbar(cnt, gen);
  }

  // ---- final: out(128,128) = q_star @ outW + outb ----
  if (bid < 128 && tid < 128){
    float acc = outb[tid];
    for (int k = 0; k < 512; k++)
      acc += q_star[bid*512 + k] * outW[k*128 + tid];
    out[bid*128 + tid] = acc;
  }
}

// ================= prep: weight bf16 conversion/packing =================
__global__ void prep_w(const float* __restrict__ W1, const float* __restrict__ W2,
    const float* __restrict__ Wih0, const float* __restrict__ Whh0,
    const float* __restrict__ Wih1, const float* __restrict__ Whh1,
    const float* __restrict__ Wih2, const float* __restrict__ Whh2,
    ushort_t* __restrict__ W1T, ushort_t* __restrict__ W2T,
    ushort_t* __restrict__ Wc0, ushort_t* __restrict__ Wc1, ushort_t* __restrict__ Wc2)
{
  int i = blockIdx.x*256 + threadIdx.x;
  if (i < 65536){
    W1T[i] = f2bf(W1[(i & 255)*256 + (i >> 8)]);
  } else if (i < 131072){
    int j = i - 65536;
    W2T[j] = f2bf(W2[(j & 255)*256 + (j >> 8)]);
  } else if (i < 131072 + 786432){
    int j = i - 131072;
    int g = j / 768, k = j - g*768;
    Wc0[j] = f2bf(k < 512 ? Wih0[g*512 + k] : Whh0[g*256 + (k - 512)]);
  } else if (i < 131072 + 786432 + 524288){
    int j = i - (131072 + 786432);
    int g = j >> 9, k = j & 511;
    Wc1[j] = f2bf(k < 256 ? Wih1[g*256 + k] : Whh1[g*256 + (k - 256)]);
  } else if (i < 131072 + 786432 + 1048576){
    int j = i - (131072 + 786432 + 524288);
    int g = j >> 9, k = j & 511;
    Wc2[j] = f2bf(k < 256 ? Wih2[g*256 + k] : Whh2[g*256 + (k - 256)]);
  }
}

// ================= prep: zeros + combined biases + segment bounds + barrier =================
__global__ void prep_misc(const float* __restrict__ bih0, const float* __restrict__ bhh0,
    const float* __restrict__ bih1, const float* __restrict__ bhh1,
    const float* __restrict__ bih2, const float* __restrict__ bhh2,
    const int* __restrict__ bidx,
    float* __restrict__ c, ushort_t* __restrict__ xc, float* __restrict__ q_star,
    float* __restrict__ bc, int* __restrict__ seg, int* __restrict__ bar)
{
  int i = blockIdx.x*256 + threadIdx.x;
  if (i < 98304) { c[i] = 0.f; return; }
  i -= 98304;
  if (i < 229376) { xc[i] = 0; return; }
  i -= 229376;
  if (i < 65536) { q_star[i] = 0.f; return; }
  i -= 65536;
  if (i < 3072) {
    int l = i >> 10, g = i & 1023;
    const float* bi = (l == 0) ? bih0 : ((l == 1) ? bih1 : bih2);
    const float* bh = (l == 0) ? bhh0 : ((l == 1) ? bhh1 : bhh2);
    bc[i] = bi[g] + bh[g];
    return;
  }
  i -= 3072;
  if (i < 129) {
    int lo = 0, hi = NN;
    while (lo < hi){ int mid = (lo + hi) >> 1; if (bidx[mid] < i) lo = mid + 1; else hi = mid; }
    seg[i] = lo;
    return;
  }
  i -= 129;
  if (i < 2) bar[i] = 0;
}

extern "C" void kernel_launch(void* const* d_in, const int* in_sizes, int n_in,
                              void* d_out, int out_size, void* d_ws, size_t ws_size,
                              hipStream_t stream)
{
  const float* x    = (const float*)d_in[0];
  const int*   bidx = (const int*)  d_in[1];
  const float* W1   = (const float*)d_in[2];
  const float* b1   = (const float*)d_in[3];
  const float* W2   = (const float*)d_in[4];
  const float* b2   = (const float*)d_in[5];
  const float* Wih0 = (const float*)d_in[6];
  const float* Whh0 = (const float*)d_in[7];
  const float* bih0 = (const float*)d_in[8];
  const float* bhh0 = (const float*)d_in[9];
  const float* Wih1 = (const float*)d_in[10];
  const float* Whh1 = (const float*)d_in[11];
  const float* bih1 = (const float*)d_in[12];
  const float* bhh1 = (const float*)d_in[13];
  const float* Wih2 = (const float*)d_in[14];
  const float* Whh2 = (const float*)d_in[15];
  const float* bih2 = (const float*)d_in[16];
  const float* bhh2 = (const float*)d_in[17];
  const float* outW = (const float*)d_in[18];
  const float* outb = (const float*)d_in[19];

  char* p = (char*)d_ws;
  auto alloc = [&](size_t bytes)->char*{ char* r = p; p += (bytes + 255) & ~(size_t)255; return r; };
  ushort_t* hfeat  = (ushort_t*)alloc((size_t)NN*256*2);   // bf16 node features
  float*    e_ws   = (float*)   alloc((size_t)NN*4);       // e, then normalized a (in place)
  ushort_t* W1T    = (ushort_t*)alloc(65536*2);
  ushort_t* W2T    = (ushort_t*)alloc(65536*2);
  ushort_t* Wc0    = (ushort_t*)alloc(786432*2);
  ushort_t* Wc1    = (ushort_t*)alloc(524288*2);
  ushort_t* Wc2    = (ushort_t*)alloc(524288*2);
  float*    bc     = (float*)   alloc(3072*4);
  float*    c_all  = (float*)   alloc(98304*4);
  ushort_t* xc     = (ushort_t*)alloc(229376*2);           // xc0(128x768)|xc1(128x512)|xc2(128x512)
  float*    q_star = (float*)   alloc(65536*4);            // (128,512) fp32
  float*    r_ws   = (float*)   alloc(32768*4);            // (128,256) fp32
  int*      seg    = (int*)     alloc(129*4);
  int*      bar    = (int*)     alloc(2*4);

  prep_w<<<7680, 256, 0, stream>>>(W1, W2, Wih0, Whh0, Wih1, Whh1, Wih2, Whh2,
                                   W1T, W2T, Wc0, Wc1, Wc2);
  prep_misc<<<1549, 256, 0, stream>>>(bih0, bhh0, bih1, bhh1, bih2, bhh2, bidx,
                                      c_all, xc, q_star, bc, seg, bar);

  fnn_fused<<<1563, 256, 0, stream>>>(x, W1T, b1, W2T, b2, hfeat, NN);

  mega<<<NBLK, 512, 0, stream>>>(hfeat, bidx, seg, Wc0, Wc1, Wc2, bc,
                                 c_all, xc, q_star, e_ws, r_ws,
                                 outW, outb, (float*)d_out, bar);
}

// Round 6
// 541.781 us; speedup vs baseline: 3.0861x; 3.0861x over previous
//
#include <hip/hip_runtime.h>

#define NN 100000
#define NSTEP 5
#define LSTR 264   // ushorts; 528B rows, 16B aligned for ds_read_b128

typedef unsigned short ushort_t;
typedef __attribute__((ext_vector_type(8))) short short8;
typedef __attribute__((ext_vector_type(4))) float floatx4;

__device__ __forceinline__ ushort_t f2bf(float f){
  union { float f; unsigned u; } v; v.f = f;
  unsigned r = v.u + 0x7fffu + ((v.u >> 16) & 1u);
  return (ushort_t)(r >> 16);
}
__device__ __forceinline__ float bf2f(ushort_t s){
  union { unsigned u; float f; } v; v.u = ((unsigned)s) << 16;
  return v.f;
}
__device__ __forceinline__ float sigf(float x){ return 1.0f/(1.0f+__expf(-x)); }

// ================= fused FNN: hfeat = (elu(x@W1+b1))@W2+b2, bf16 out =================
// 1563 blocks x 256 thr (4 waves), 64 rows x 256 cols, 33.8 KB LDS.
// Weights in fragment-major layout: B-frag = ONE coalesced 1KB wave load.
__global__ __launch_bounds__(256, 4) void fnn_fused(const float* __restrict__ x,
    const ushort_t* __restrict__ W1P, const float* __restrict__ b1,
    const ushort_t* __restrict__ W2P, const float* __restrict__ b2,
    ushort_t* __restrict__ hfeat, int M)
{
  __shared__ ushort_t buf[64 * LSTR];
  int tid = threadIdx.x;
  int w = tid >> 6, lane = tid & 63, qd = lane >> 4, r16 = lane & 15;
  int row0 = blockIdx.x * 64;
  int col0 = w * 64;

  // ---- stage x tile (64x256 fp32 -> bf16 LDS) ----
  #pragma unroll
  for (int it = 0; it < 16; it++){
    int idx = it * 256 + tid;
    int r = idx >> 6, c4 = idx & 63;
    int rg = row0 + r; if (rg >= M) rg = M - 1;
    float4 v = *(const float4*)(x + (size_t)rg * 256 + c4 * 4);
    ushort4 pk = make_ushort4(f2bf(v.x), f2bf(v.y), f2bf(v.z), f2bf(v.w));
    *(ushort4*)&buf[r * LSTR + c4 * 4] = pk;
  }
  __syncthreads();

  floatx4 acc[4][4];

  // ---- GEMM1 ----
  #pragma unroll
  for (int i=0;i<4;i++)
    #pragma unroll
    for (int j=0;j<4;j++) acc[i][j] = (floatx4){0.f,0.f,0.f,0.f};

  for (int kc = 0; kc < 8; kc++){
    short8 af[4], bfr[4];
    #pragma unroll
    for (int i=0;i<4;i++)
      af[i] = *(const short8*)&buf[(i*16 + r16) * LSTR + kc*32 + qd*8];
    #pragma unroll
    for (int j=0;j<4;j++)
      bfr[j] = *(const short8*)(W1P + (size_t)(((w*4 + j)*8 + kc)*64 + lane)*8);
    #pragma unroll
    for (int i=0;i<4;i++)
      #pragma unroll
      for (int j=0;j<4;j++)
        acc[i][j] = __builtin_amdgcn_mfma_f32_16x16x32_bf16(af[i], bfr[j], acc[i][j], 0, 0, 0);
  }
  __syncthreads();

  // ---- ELU -> t tile in same LDS ----
  #pragma unroll
  for (int i=0;i<4;i++){
    #pragma unroll
    for (int j=0;j<4;j++){
      int col = col0 + j*16 + r16;
      float bb = b1[col];
      #pragma unroll
      for (int rr=0;rr<4;rr++){
        int row = i*16 + qd*4 + rr;
        float v = acc[i][j][rr] + bb;
        v = v > 0.f ? v : (__expf(v) - 1.0f);
        buf[row * LSTR + col] = f2bf(v);
      }
    }
  }
  __syncthreads();

  // ---- GEMM2 ----
  #pragma unroll
  for (int i=0;i<4;i++)
    #pragma unroll
    for (int j=0;j<4;j++) acc[i][j] = (floatx4){0.f,0.f,0.f,0.f};

  for (int kc = 0; kc < 8; kc++){
    short8 af[4], bfr[4];
    #pragma unroll
    for (int i=0;i<4;i++)
      af[i] = *(const short8*)&buf[(i*16 + r16) * LSTR + kc*32 + qd*8];
    #pragma unroll
    for (int j=0;j<4;j++)
      bfr[j] = *(const short8*)(W2P + (size_t)(((w*4 + j)*8 + kc)*64 + lane)*8);
    #pragma unroll
    for (int i=0;i<4;i++)
      #pragma unroll
      for (int j=0;j<4;j++)
        acc[i][j] = __builtin_amdgcn_mfma_f32_16x16x32_bf16(af[i], bfr[j], acc[i][j], 0, 0, 0);
  }

  #pragma unroll
  for (int i=0;i<4;i++){
    #pragma unroll
    for (int j=0;j<4;j++){
      int col = col0 + j*16 + r16;
      float bb = b2[col];
      #pragma unroll
      for (int rr=0;rr<4;rr++){
        int row = row0 + i*16 + qd*4 + rr;
        if (row < M) hfeat[(size_t)row * 256 + col] = f2bf(acc[i][j][rr] + bb);
      }
    }
  }
}

// ================= LSTM layer: gates GEMM (K-split x4 waves) + fused cell =================
// 128 blocks x 256. Block = (m0 = 16 rows, nt = 16 h-cols) x 4 gates. Weights fragment-major.
__global__ __launch_bounds__(256) void lstm_layer(const ushort_t* __restrict__ A, int lda,
    const ushort_t* __restrict__ WcP, const float* __restrict__ bcp, int KC,
    float* __restrict__ c, ushort_t* __restrict__ dstA, int sA,
    ushort_t* __restrict__ dstB, int sB, float* __restrict__ qdst)
{
  __shared__ float sbuf[3][4][256];
  int tid = threadIdx.x, w = tid >> 6, lane = tid & 63, qd = lane >> 4, r16 = lane & 15;
  int m0 = (blockIdx.x & 7) * 16, nt = blockIdx.x >> 3;
  int kcq = KC >> 2;                       // chunks per wave: 6 (K=768) or 4 (K=512)
  int kc0 = w * kcq;

  floatx4 acc[4];
  #pragma unroll
  for (int g=0; g<4; g++) acc[g] = (floatx4){0.f,0.f,0.f,0.f};

  const ushort_t* Ar = A + (size_t)(m0 + r16) * lda + qd * 8;
  for (int kc = kc0; kc < kc0 + kcq; kc++){
    short8 av = *(const short8*)(Ar + kc*32);
    #pragma unroll
    for (int g = 0; g < 4; g++){
      short8 bv = *(const short8*)(WcP + (size_t)((((g*16 + nt)*KC) + kc)*64 + lane)*8);
      acc[g] = __builtin_amdgcn_mfma_f32_16x16x32_bf16(av, bv, acc[g], 0, 0, 0);
    }
  }
  if (w){
    #pragma unroll
    for (int g=0; g<4; g++) *(floatx4*)&sbuf[w-1][g][lane*4] = acc[g];
  }
  __syncthreads();
  if (w == 0){
    #pragma unroll
    for (int g=0; g<4; g++)
      #pragma unroll
      for (int t=0; t<3; t++){
        floatx4 p = *(floatx4*)&sbuf[t][g][lane*4];
        acc[g] = acc[g] + p;
      }
    int h = nt*16 + r16;
    float bci = bcp[h], bcf = bcp[256+h], bcg = bcp[512+h], bco = bcp[768+h];
    #pragma unroll
    for (int rr=0; rr<4; rr++){
      int row = m0 + qd*4 + rr;
      float gi = acc[0][rr] + bci;
      float gf = acc[1][rr] + bcf;
      float gg = acc[2][rr] + bcg;
      float go = acc[3][rr] + bco;
      float cp = c[row*256 + h];
      float cn = sigf(gf)*cp + sigf(gi)*tanhf(gg);
      float hn = sigf(go)*tanhf(cn);
      c[row*256 + h] = cn;
      ushort_t hb = f2bf(hn);
      dstA[row*sA + h] = hb;
      dstB[row*sB + h] = hb;
      if (qdst) qdst[row*512 + h] = hn;
    }
  }
}

// ================= one-pass attention: S[b] += exp(e_n)*h_n, Z[b] += exp(e_n) =================
// 512 blocks x 256 thr: 2048 waves, wave = 49 contiguous (sorted) nodes. No max-subtract
// (|e| ~ O(10) << 88, fp32 exp safe); softmax normalization happens in attn_fin.
__global__ __launch_bounds__(256) void attn_onepass(const ushort_t* __restrict__ hfeat,
    const int* __restrict__ bidx, const float* __restrict__ q_star,
    float* __restrict__ r_acc, float* __restrict__ z_acc)
{
  const int CH = (NN + 2047) / 2048;       // 49
  int gw = blockIdx.x*4 + (threadIdx.x >> 6);
  int lane = threadIdx.x & 63;
  int n0 = gw * CH;
  int nend = n0 + CH; if (nend > NN) nend = NN;
  if (n0 >= nend) return;

  int bcur = bidx[n0];
  float4 q = *(const float4*)(q_star + (size_t)bcur*512 + lane*4);
  float S0=0.f, S1=0.f, S2=0.f, S3=0.f, Z=0.f;

  ushort4 h = *(const ushort4*)(hfeat + (size_t)n0*256 + lane*4);
  for (int n = n0; n < nend; n++){
    ushort4 hn;
    int bn = bcur;
    if (n + 1 < nend){
      hn = *(const ushort4*)(hfeat + (size_t)(n+1)*256 + lane*4);
      bn = bidx[n+1];
    }
    float f0 = bf2f(h.x), f1 = bf2f(h.y), f2 = bf2f(h.z), f3 = bf2f(h.w);
    float d = f0*q.x + f1*q.y + f2*q.z + f3*q.w;
    #pragma unroll
    for (int off = 32; off; off >>= 1) d += __shfl_xor(d, off);
    float wgt = __expf(d);
    Z += wgt;
    S0 += wgt*f0; S1 += wgt*f1; S2 += wgt*f2; S3 += wgt*f3;
    if (bn != bcur){
      float* rp = r_acc + bcur*256 + lane*4;
      atomicAdd(rp+0, S0); atomicAdd(rp+1, S1);
      atomicAdd(rp+2, S2); atomicAdd(rp+3, S3);
      if (lane == 0) atomicAdd(&z_acc[bcur], Z);
      S0=S1=S2=S3=Z=0.f;
      bcur = bn;
      q = *(const float4*)(q_star + (size_t)bcur*512 + lane*4);
    }
    h = hn;
  }
  float* rp = r_acc + bcur*256 + lane*4;
  atomicAdd(rp+0, S0); atomicAdd(rp+1, S1);
  atomicAdd(rp+2, S2); atomicAdd(rp+3, S3);
  if (lane == 0) atomicAdd(&z_acc[bcur], Z);
}

// ================= finalize: r = S/Z -> q_star/xc0; zero acc; last: output GEMM =================
__global__ __launch_bounds__(256) void attn_fin(float* __restrict__ r_acc,
    float* __restrict__ z_acc, float* __restrict__ q_star, ushort_t* __restrict__ xc0,
    const float* __restrict__ outW, const float* __restrict__ outb,
    float* __restrict__ out, int last)
{
  __shared__ float qs[512];
  int b = blockIdx.x, f = threadIdx.x;
  float v = r_acc[b*256 + f] / (z_acc[b] + 1e-16f);
  q_star[b*512 + 256 + f] = v;
  xc0[b*768 + 256 + f] = f2bf(v);
  r_acc[b*256 + f] = 0.f;
  if (f == 0) z_acc[b] = 0.f;
  if (last){
    qs[f] = q_star[b*512 + f];     // q half (written by lstm2, prior dispatch)
    qs[256 + f] = v;               // r half (computed here)
    __syncthreads();
    if (f < 128){
      float acc = outb[f];
      for (int k = 0; k < 512; k++) acc += qs[k] * outW[k*128 + f];
      out[b*128 + f] = acc;
    }
  }
}

// ================= prep: fragment-major weight packing + all zero/init =================
// Packed layout per 16-col tile T, 32-k chunk kc: [(T*KC + kc)*64 + lane]*8 + j,
// where lane holds BT[n = T*16 + (lane&15)][k = kc*32 + (lane>>4)*8 + j].
__global__ void prep_all(const float* __restrict__ W1, const float* __restrict__ W2,
    const float* __restrict__ Wih0, const float* __restrict__ Whh0,
    const float* __restrict__ Wih1, const float* __restrict__ Whh1,
    const float* __restrict__ Wih2, const float* __restrict__ Whh2,
    const float* __restrict__ bih0, const float* __restrict__ bhh0,
    const float* __restrict__ bih1, const float* __restrict__ bhh1,
    const float* __restrict__ bih2, const float* __restrict__ bhh2,
    const int* __restrict__ bidx,
    ushort_t* __restrict__ W1P, ushort_t* __restrict__ W2P,
    ushort_t* __restrict__ Wc0P, ushort_t* __restrict__ Wc1P, ushort_t* __restrict__ Wc2P,
    float* __restrict__ c, ushort_t* __restrict__ xc, float* __restrict__ q_star,
    float* __restrict__ bc, int* __restrict__ seg,
    float* __restrict__ r_acc, float* __restrict__ z_acc)
{
  int i = blockIdx.x*256 + threadIdx.x;
  // --- W1P / W2P: K=256, KC=8, tile size 4096 ---
  if (i < 131072){
    const float* W = (i < 65536) ? W1 : W2;
    ushort_t* P = (i < 65536) ? W1P : W2P;
    int r = i & 65535;
    int T = r >> 12, r2 = r & 4095;
    int kc = r2 >> 9, l = (r2 >> 3) & 63, j = r2 & 7;
    int k = kc*32 + ((l>>4)<<3) + j;
    int n = T*16 + (l & 15);
    P[r] = f2bf(W[k*256 + n]);
    return;
  }
  i -= 131072;
  // --- Wc0P: K=768, KC=24, tile size 12288, 64 tiles ---
  if (i < 786432){
    int T = i / 12288, r2 = i - T*12288;
    int kc = r2 >> 9, l = (r2 >> 3) & 63, j = r2 & 7;
    int k = kc*32 + ((l>>4)<<3) + j;
    int g = T >> 4, n = (T & 15)*16 + (l & 15);
    int row = g*256 + n;
    Wc0P[i] = f2bf(k < 512 ? Wih0[row*512 + k] : Whh0[row*256 + (k - 512)]);
    return;
  }
  i -= 786432;
  // --- Wc1P / Wc2P: K=512, KC=16, tile size 8192, 64 tiles each ---
  if (i < 1048576){
    const float* Wih = (i < 524288) ? Wih1 : Wih2;
    const float* Whh = (i < 524288) ? Whh1 : Whh2;
    ushort_t* P = (i < 524288) ? Wc1P : Wc2P;
    int r = i & 524287;
    int T = r >> 13, r2 = r & 8191;
    int kc = r2 >> 9, l = (r2 >> 3) & 63, j = r2 & 7;
    int k = kc*32 + ((l>>4)<<3) + j;
    int g = T >> 4, n = (T & 15)*16 + (l & 15);
    int row = g*256 + n;
    P[r] = f2bf(k < 256 ? Wih[row*256 + k] : Whh[row*256 + (k - 256)]);
    return;
  }
  i -= 1048576;
  if (i < 98304) { c[i] = 0.f; return; }
  i -= 98304;
  if (i < 229376) { xc[i] = 0; return; }
  i -= 229376;
  if (i < 65536) { q_star[i] = 0.f; return; }
  i -= 65536;
  if (i < 3072) {
    int l = i >> 10, g = i & 1023;
    const float* bi = (l == 0) ? bih0 : ((l == 1) ? bih1 : bih2);
    const float* bh = (l == 0) ? bhh0 : ((l == 1) ? bhh1 : bhh2);
    bc[i] = bi[g] + bh[g];
    return;
  }
  i -= 3072;
  if (i < 129) {
    int lo = 0, hi = NN;
    while (lo < hi){ int mid = (lo + hi) >> 1; if (bidx[mid] < i) lo = mid + 1; else hi = mid; }
    seg[i] = lo;
    return;
  }
  i -= 129;
  if (i < 32768) { r_acc[i] = 0.f; return; }
  i -= 32768;
  if (i < 128) z_acc[i] = 0.f;
}

extern "C" void kernel_launch(void* const* d_in, const int* in_sizes, int n_in,
                              void* d_out, int out_size, void* d_ws, size_t ws_size,
                              hipStream_t stream)
{
  const float* x    = (const float*)d_in[0];
  const int*   bidx = (const int*)  d_in[1];
  const float* W1   = (const float*)d_in[2];
  const float* b1   = (const float*)d_in[3];
  const float* W2   = (const float*)d_in[4];
  const float* b2   = (const float*)d_in[5];
  const float* Wih0 = (const float*)d_in[6];
  const float* Whh0 = (const float*)d_in[7];
  const float* bih0 = (const float*)d_in[8];
  const float* bhh0 = (const float*)d_in[9];
  const float* Wih1 = (const float*)d_in[10];
  const float* Whh1 = (const float*)d_in[11];
  const float* bih1 = (const float*)d_in[12];
  const float* bhh1 = (const float*)d_in[13];
  const float* Wih2 = (const float*)d_in[14];
  const float* Whh2 = (const float*)d_in[15];
  const float* bih2 = (const float*)d_in[16];
  const float* bhh2 = (const float*)d_in[17];
  const float* outW = (const float*)d_in[18];
  const float* outb = (const float*)d_in[19];

  char* p = (char*)d_ws;
  auto alloc = [&](size_t bytes)->char*{ char* r = p; p += (bytes + 255) & ~(size_t)255; return r; };
  ushort_t* hfeat  = (ushort_t*)alloc((size_t)NN*256*2);   // bf16 node features
  ushort_t* W1P    = (ushort_t*)alloc(65536*2);
  ushort_t* W2P    = (ushort_t*)alloc(65536*2);
  ushort_t* Wc0P   = (ushort_t*)alloc(786432*2);
  ushort_t* Wc1P   = (ushort_t*)alloc(524288*2);
  ushort_t* Wc2P   = (ushort_t*)alloc(524288*2);
  float*    bc     = (float*)   alloc(3072*4);
  float*    c_all  = (float*)   alloc(98304*4);
  ushort_t* xc     = (ushort_t*)alloc(229376*2);           // xc0(128x768)|xc1(128x512)|xc2(128x512)
  float*    q_star = (float*)   alloc(65536*4);            // (128,512) fp32
  float*    r_acc  = (float*)   alloc(32768*4);            // (128,256) fp32
  float*    z_acc  = (float*)   alloc(128*4);
  int*      seg    = (int*)     alloc(129*4);

  ushort_t* xc0 = xc;
  ushort_t* xc1 = xc + 98304;
  ushort_t* xc2 = xc + 163840;
  float* c0 = c_all, *c1 = c_all + 32768, *c2 = c_all + 65536;
  float* bc0 = bc, *bc1 = bc + 1024, *bc2 = bc + 2048;

  prep_all<<<9357, 256, 0, stream>>>(W1, W2, Wih0, Whh0, Wih1, Whh1, Wih2, Whh2,
                                     bih0, bhh0, bih1, bhh1, bih2, bhh2, bidx,
                                     W1P, W2P, Wc0P, Wc1P, Wc2P,
                                     c_all, xc, q_star, bc, seg, r_acc, z_acc);

  fnn_fused<<<1563, 256, 0, stream>>>(x, W1P, b1, W2P, b2, hfeat, NN);

  for (int s = 0; s < NSTEP; s++){
    // layer 0: in = [q_star | h0_prev] (K=768, KC=24)
    lstm_layer<<<128, 256, 0, stream>>>(xc0, 768, Wc0P, bc0, 24, c0, xc0 + 512, 768, xc1, 512, nullptr);
    // layer 1: in = [h0 | h1_prev] (K=512, KC=16)
    lstm_layer<<<128, 256, 0, stream>>>(xc1, 512, Wc1P, bc1, 16, c1, xc1 + 256, 512, xc2, 512, nullptr);
    // layer 2: in = [h1 | h2_prev] (K=512); h2 = q
    lstm_layer<<<128, 256, 0, stream>>>(xc2, 512, Wc2P, bc2, 16, c2, xc2 + 256, 512, xc0, 768, q_star);
    // one-pass attention + finalize (last step folds in the output GEMM)
    attn_onepass<<<512, 256, 0, stream>>>(hfeat, bidx, q_star, r_acc, z_acc);
    attn_fin<<<128, 256, 0, stream>>>(r_acc, z_acc, q_star, xc0, outW, outb,
                                      (float*)d_out, s == NSTEP-1 ? 1 : 0);
  }
}